// Round 1
// baseline (1617.085 us; speedup 1.0000x reference)
//
#include <hip/hip_runtime.h>
#include <math.h>

#define B_   32
#define C_   256
#define H_   80
#define W_   80
#define MID_ 64
#define HW_  (H_*W_)      // 6400
#define H2_  160
#define W2_  160
#define HW2_ (H2_*W2_)    // 25600

// ---------------------------------------------------------------------------
// Kernel 1: fused 1x1 conv (C->MID) + relu + 1x1 conv (MID->8) + tanh
// One thread per (b,h,w) pixel. w1 staged in LDS transposed ([c][m]) so the
// m-loop reads are contiguous (ds_read_b128) and wave-uniform (broadcast, no
// bank conflicts). 64 fp32 accumulators live in VGPRs.
// ---------------------------------------------------------------------------
__global__ __launch_bounds__(256) void offsets_kernel(
    const float* __restrict__ x, const float* __restrict__ w1,
    const float* __restrict__ w2, const float* __restrict__ b2,
    float* __restrict__ off)
{
    __shared__ float w1s[C_*MID_];   // [c][m]
    __shared__ float w2s[8*MID_];    // [o][m]
    __shared__ float b2s[8];

    // load w1 transposed: w1[m*C_+c] -> w1s[c*MID_+m]
    // (uncoalesced 64KB global read, one-time; LDS writes are contiguous)
    for (int idx = threadIdx.x; idx < C_*MID_; idx += 256) {
        int m = idx & (MID_-1);
        int c = idx >> 6;
        w1s[idx] = w1[m*C_ + c];
    }
    for (int idx = threadIdx.x; idx < 8*MID_; idx += 256) w2s[idx] = w2[idx];
    if (threadIdx.x < 8) b2s[threadIdx.x] = b2[threadIdx.x];
    __syncthreads();

    int p  = blockIdx.x * 256 + threadIdx.x;   // global pixel id, exact grid
    int b  = p / HW_;
    int hw = p - b*HW_;
    const float* xp = x + (size_t)b*C_*HW_ + hw;

    float hid[MID_];
    #pragma unroll
    for (int m = 0; m < MID_; ++m) hid[m] = 0.f;

    #pragma unroll 4
    for (int c = 0; c < C_; ++c) {
        float xv = xp[(size_t)c*HW_];          // coalesced across lanes
        const float* wrow = &w1s[c*MID_];
        #pragma unroll
        for (int m = 0; m < MID_; ++m) hid[m] = fmaf(xv, wrow[m], hid[m]);
    }
    #pragma unroll
    for (int m = 0; m < MID_; ++m) hid[m] = fmaxf(hid[m], 0.f);

    float* op = off + (size_t)b*8*HW_ + hw;
    #pragma unroll
    for (int o = 0; o < 8; ++o) {
        float acc = b2s[o];
        #pragma unroll
        for (int m = 0; m < MID_; ++m) acc = fmaf(hid[m], w2s[o*MID_+m], acc);
        op[o*HW_] = tanhf(acc);               // coalesced store
    }
}

// ---------------------------------------------------------------------------
// Kernel 2: bilinear sample (border clamp, align-corners mapping) + 2x2
// pixel-shuffle. One thread per (b,h,w); the 4 sub-pixel taps' weights and
// neighbor offsets are computed once, then reused across all 256 channels.
// Stores: two coalesced float2 per channel (rows 2h and 2h+1).
// ---------------------------------------------------------------------------
__global__ __launch_bounds__(256) void sample_kernel(
    const float* __restrict__ x, const float* __restrict__ off,
    float* __restrict__ out)
{
    int p  = blockIdx.x * 256 + threadIdx.x;
    int b  = p / HW_;
    int hw = p - b*HW_;
    int h  = hw / W_;
    int w  = hw - h*W_;

    const float* offp = off + (size_t)b*8*HW_ + hw;

    float wgt[4][4];
    int   ofs[4][4];
    #pragma unroll
    for (int k = 0; k < 4; ++k) {
        int i = k >> 1, j = k & 1;             // k = i*S + j
        float ox = offp[k*HW_];
        float oy = offp[(4+k)*HW_];
        float gx = -1.f + (2.f*(float)(2*w+j) + 1.f) * (1.f/(float)W2_);
        float gy = -1.f + (2.f*(float)(2*h+i) + 1.f) * (1.f/(float)H2_);
        float sx = gx + ox * (2.f/(float)W2_);
        float sy = gy + oy * (2.f/(float)H2_);
        float ix = (sx + 1.f) * 0.5f * (float)(W_-1);
        float iy = (sy + 1.f) * 0.5f * (float)(H_-1);
        ix = fminf(fmaxf(ix, 0.f), (float)(W_-1));
        iy = fminf(fmaxf(iy, 0.f), (float)(H_-1));
        float xf = floorf(ix), yf = floorf(iy);
        int   x0 = (int)xf,    y0 = (int)yf;
        float wx = ix - xf,    wy = iy - yf;
        int   x1 = min(x0+1, W_-1), y1 = min(y0+1, H_-1);
        wgt[k][0] = (1.f-wx)*(1.f-wy);
        wgt[k][1] = wx*(1.f-wy);
        wgt[k][2] = (1.f-wx)*wy;
        wgt[k][3] = wx*wy;
        ofs[k][0] = y0*W_ + x0;
        ofs[k][1] = y0*W_ + x1;
        ofs[k][2] = y1*W_ + x0;
        ofs[k][3] = y1*W_ + x1;
    }

    const float* xb = x   + (size_t)b*C_*HW_;
    float*       ob = out + (size_t)b*C_*HW2_ + (size_t)(2*h)*W2_ + 2*w;

    for (int c = 0; c < C_; ++c) {
        const float* xc = xb + (size_t)c*HW_;
        float v[4];
        #pragma unroll
        for (int k = 0; k < 4; ++k) {
            v[k] = xc[ofs[k][0]]*wgt[k][0] + xc[ofs[k][1]]*wgt[k][1]
                 + xc[ofs[k][2]]*wgt[k][2] + xc[ofs[k][3]]*wgt[k][3];
        }
        float* oc = ob + (size_t)c*HW2_;
        *reinterpret_cast<float2*>(oc)        = make_float2(v[0], v[1]);
        *reinterpret_cast<float2*>(oc + W2_)  = make_float2(v[2], v[3]);
    }
}

extern "C" void kernel_launch(void* const* d_in, const int* in_sizes, int n_in,
                              void* d_out, int out_size, void* d_ws, size_t ws_size,
                              hipStream_t stream) {
    const float* x  = (const float*)d_in[0];
    const float* w1 = (const float*)d_in[1];
    const float* w2 = (const float*)d_in[2];
    const float* b2 = (const float*)d_in[3];
    float* out = (float*)d_out;
    float* off = (float*)d_ws;   // 8*B*H*W floats = 6.55 MB scratch

    const int npix = B_*HW_;     // 204800 = 800 * 256 exactly
    offsets_kernel<<<npix/256, 256, 0, stream>>>(x, w1, w2, b2, off);
    sample_kernel <<<npix/256, 256, 0, stream>>>(x, off, out);
}